// Round 3
// baseline (1954.770 us; speedup 1.0000x reference)
//
#include <hip/hip_runtime.h>
#include <stdint.h>

#define NNODES 4096
#define HDIM   128
#define NE     8
#define KXX    2176   // 2*E*H + H  (msg | h)
#define NG     512    // gate cols: [ir+hr | iz+hz | inn | hn]

typedef unsigned short u16;
typedef __bf16 bf8v __attribute__((ext_vector_type(8)));
typedef float  f4v   __attribute__((ext_vector_type(4)));

static __device__ __forceinline__ float bf2f(u16 u) {
    union { unsigned int i; float f; } x; x.i = ((unsigned int)u) << 16; return x.f;
}
static __device__ __forceinline__ u16 f2bf(float f) {
    union { float f; unsigned int i; } x; x.f = f;
    unsigned int r = x.i + 0x7fffu + ((x.i >> 16) & 1u);   // RTNE
    return (u16)(r >> 16);
}
// XOR swizzle on 8-element chunks (flips bits 3..5 of col index; preserves
// 16B contiguity of 8-element groups).
static __device__ __forceinline__ int swz(int r, int c) {
    return r * 64 + (c ^ ((((r >> 3) ^ r) & 7) << 3));
}
static __device__ __forceinline__ f4v mfma16(bf8v a, bf8v b, f4v c) {
    return __builtin_amdgcn_mfma_f32_16x16x32_bf16(a, b, c, 0, 0, 0);
}
static __device__ __forceinline__ bf8v lds_frag(const u16* p) {
    return *(const bf8v*)p;
}
// split 8 floats -> hi/lo bf16 (each 16B), from two float4s
static __device__ __forceinline__ void split8(const float* g, u16* vh, u16* vl) {
    float4 v0 = *(const float4*)g;
    float4 v1 = *(const float4*)(g + 4);
    float vs[8] = {v0.x, v0.y, v0.z, v0.w, v1.x, v1.y, v1.z, v1.w};
    #pragma unroll
    for (int q = 0; q < 8; q++) {
        u16 hi = f2bf(vs[q]);
        vh[q] = hi;
        vl[q] = f2bf(vs[q] - bf2f(hi));
    }
}
static __device__ __forceinline__ void cvt8(const float* g, u16* vh) {
    float4 v0 = *(const float4*)g;
    float4 v1 = *(const float4*)(g + 4);
    float vs[8] = {v0.x, v0.y, v0.z, v0.w, v1.x, v1.y, v1.z, v1.w};
    #pragma unroll
    for (int q = 0; q < 8; q++) vh[q] = f2bf(vs[q]);
}

// ---------------- K0: h = tanh([emb[ids], node_states] @ W_init + b_init) ----
__global__ void k0_init(const float* __restrict__ nst, const int* __restrict__ ids,
                        const float* __restrict__ emb, const float* __restrict__ Wi,
                        const float* __restrict__ bi, float* __restrict__ h,
                        float* __restrict__ X)
{
    __shared__ float ni[16][384];
    const int n0 = blockIdx.x * 16;
    const int tid = threadIdx.x;   // 128 threads
    for (int idx = tid; idx < 16 * 384; idx += 128) {
        int r = idx / 384, c = idx - r * 384;
        float v;
        if (c < 128) v = emb[(size_t)ids[n0 + r] * 128 + c];
        else         v = nst[(size_t)(n0 + r) * 256 + (c - 128)];
        ni[r][c] = v;
    }
    __syncthreads();
    float acc[16];
    #pragma unroll
    for (int r = 0; r < 16; r++) acc[r] = 0.f;
    for (int c = 0; c < 384; c++) {
        float w = Wi[c * 128 + tid];
        #pragma unroll
        for (int r = 0; r < 16; r++) acc[r] += ni[r][c] * w;
    }
    float bb = bi[tid];
    #pragma unroll
    for (int r = 0; r < 16; r++) {
        float v = tanhf(acc[r] + bb);
        h[(size_t)(n0 + r) * HDIM + tid] = v;
        X[(size_t)(n0 + r) * KXX + 2048 + tid] = v;
    }
}

// ---------------- Kprep: pack W' rows j over cols c of X (bf16) --------------
__global__ void kprep(const float* __restrict__ Wx, const float* __restrict__ bx,
                      const float* __restrict__ Wh, const float* __restrict__ bh,
                      u16* __restrict__ WT, float* __restrict__ bv)
{
    const int j = blockIdx.x;  // 0..511
    for (int c = threadIdx.x; c < KXX; c += blockDim.x) {
        float v;
        if (j < 384) {
            if (c < 2048) v = Wx[(size_t)c * 384 + j];
            else          v = (j < 256) ? Wh[(size_t)(c - 2048) * 384 + j] : 0.f;
        } else {
            if (c < 2048) v = 0.f;
            else          v = Wh[(size_t)(c - 2048) * 384 + (j - 128)];
        }
        WT[(size_t)j * KXX + c] = f2bf(v);
    }
    if (threadIdx.x == 0) {
        float b;
        if (j < 256)      b = bx[j] + bh[j];
        else if (j < 384) b = bx[j];
        else              b = bh[j - 128];
        bv[j] = b;
    }
}

// ---------------- K1: hoT[dir][e][k][m] = tanh(h @ W + b)^T  (single bf16) ---
__global__ __launch_bounds__(256, 3) void k1_hoT(const float* __restrict__ h,
        const float* __restrict__ Wo, const float* __restrict__ bo,
        const float* __restrict__ Wn, const float* __restrict__ bn,
        u16* __restrict__ hoT)
{
    const int mt = blockIdx.x, e = blockIdx.y, dir = blockIdx.z;
    const float* W    = (dir == 0 ? Wo : Wn) + (size_t)e * HDIM * HDIM;  // [j][k]
    const float* bias = (dir == 0 ? bo : bn) + (size_t)e * HDIM;
    const int m0 = mt * 128;
    const int tid = threadIdx.x, lane = tid & 63, wv = tid >> 6;
    const int wrow0 = (wv & 1) * 64, wcol0 = (wv >> 1) * 64;
    const int lrow = lane & 15, lkb = (lane >> 4) * 8;

    __shared__ __align__(16) u16 lWT[128 * 64];   // [k-out][j-tile]
    __shared__ __align__(16) u16 lB [128 * 64];   // [m][j-tile]

    f4v acc[4][4];
    #pragma unroll
    for (int i = 0; i < 4; i++)
        #pragma unroll
        for (int j = 0; j < 4; j++)
            #pragma unroll
            for (int q = 0; q < 4; q++) acc[i][j][q] = 0.f;

    for (int jt = 0; jt < 128; jt += 64) {
        __syncthreads();
        {   // lWT[k][j] = W[jt+j][k]  (transpose scatter, f32->bf16)
            int jj = tid >> 4;
            int kc = (tid & 15) * 8;
            #pragma unroll
            for (int p = 0; p < 4; p++) {
                u16 vh[8];
                cvt8(W + (size_t)(jt + jj + 16 * p) * HDIM + kc, vh);
                #pragma unroll
                for (int q = 0; q < 8; q++) lWT[swz(kc + q, jj + 16 * p)] = vh[q];
            }
        }
        {   // lB[m][j] = bf16(h[m0+m][jt+j])
            int m = tid >> 3;
            int jc = (tid & 7) * 8;
            #pragma unroll
            for (int p = 0; p < 4; p++) {
                u16 vh[8];
                cvt8(h + (size_t)(m0 + m + 32 * p) * HDIM + jt + jc, vh);
                *(uint4*)&lB[swz(m + 32 * p, jc)] = *(const uint4*)vh;
            }
        }
        __syncthreads();
        #pragma unroll
        for (int ks = 0; ks < 2; ks++) {
            const int kb = ks * 32 + lkb;
            bf8v a[4], b8[4];
            #pragma unroll
            for (int i = 0; i < 4; i++)
                a[i] = lds_frag(&lWT[swz(wrow0 + 16 * i + lrow, kb)]);
            #pragma unroll
            for (int j = 0; j < 4; j++)
                b8[j] = lds_frag(&lB[swz(wcol0 + 16 * j + lrow, kb)]);
            #pragma unroll
            for (int i = 0; i < 4; i++)
                #pragma unroll
                for (int j = 0; j < 4; j++)
                    acc[i][j] = mfma16(a[i], b8[j], acc[i][j]);
        }
    }
    u16* dst = hoT + (size_t)(dir * NE + e) * HDIM * NNODES;
    #pragma unroll
    for (int i = 0; i < 4; i++)
        #pragma unroll
        for (int j = 0; j < 4; j++)
            #pragma unroll
            for (int reg = 0; reg < 4; reg++) {
                int k = wrow0 + 16 * i + (lane >> 4) * 4 + reg;   // C/D row (M)
                int m = wcol0 + 16 * j + (lane & 15);             // C/D col (N)
                float v = tanhf(acc[i][j][reg] + bias[k]);
                dst[(size_t)k * NNODES + m0 + m] = f2bf(v);
            }
}

// ---------------- K2: dir0: mo = A @ ho ; dir1: mi = A^T @ hi ----------------
// A is fp32; staged to LDS as hi/lo bf16 pair. ho single bf16. X out fp32.
__global__ __launch_bounds__(256, 3) void k2_msg(const float* __restrict__ A,
        const u16* __restrict__ hoT, float* __restrict__ X)
{
    const int l = blockIdx.x;                 // XCD-affinity: e = l % 8
    const int nt = (l >> 3) & 31;
    const int g = (l & 7) | ((l >> 8) << 3);
    const int e = g & 7, dir = g >> 3;
    const int n0 = nt * 128;
    const int tid = threadIdx.x, lane = tid & 63, wv = tid >> 6;
    const int wrow0 = (wv & 1) * 64, wcol0 = (wv >> 1) * 64;
    const int lrow = lane & 15, lkb = (lane >> 4) * 8;

    __shared__ __align__(16) u16 lAh[128 * 64];   // [n][m-tile] hi
    __shared__ __align__(16) u16 lAl[128 * 64];   // lo
    __shared__ __align__(16) u16 lB [128 * 64];   // [k-feat][m-tile]

    const float* Ae = A   + (size_t)e * NNODES * NNODES;
    const u16*   B  = hoT + (size_t)(dir * NE + e) * HDIM * NNODES;

    f4v acc[4][4];
    #pragma unroll
    for (int i = 0; i < 4; i++)
        #pragma unroll
        for (int j = 0; j < 4; j++)
            #pragma unroll
            for (int q = 0; q < 4; q++) acc[i][j][q] = 0.f;

    for (int m0 = 0; m0 < NNODES; m0 += 64) {
        __syncthreads();
        if (dir == 0) {           // lA[n][m] = A[n0+n][m0+m]
            int r = tid >> 3, c = (tid & 7) * 8;
            #pragma unroll
            for (int p = 0; p < 4; p++) {
                u16 vh[8], vl[8];
                split8(Ae + (size_t)(n0 + r + 32 * p) * NNODES + m0 + c, vh, vl);
                *(uint4*)&lAh[swz(r + 32 * p, c)] = *(const uint4*)vh;
                *(uint4*)&lAl[swz(r + 32 * p, c)] = *(const uint4*)vl;
            }
        } else {                  // lA[n][m] = A[m0+m][n0+n]  (transpose scatter)
            int mm = tid >> 4, nn = (tid & 15) * 8;
            #pragma unroll
            for (int p = 0; p < 4; p++) {
                u16 vh[8], vl[8];
                split8(Ae + (size_t)(m0 + mm + 16 * p) * NNODES + n0 + nn, vh, vl);
                #pragma unroll
                for (int q = 0; q < 8; q++) {
                    lAh[swz(nn + q, mm + 16 * p)] = vh[q];
                    lAl[swz(nn + q, mm + 16 * p)] = vl[q];
                }
            }
        }
        {   // lB[k][m] = hoT[k][m0+m]
            int r = tid >> 3, c = (tid & 7) * 8;
            #pragma unroll
            for (int p = 0; p < 4; p++)
                *(uint4*)&lB[swz(r + 32 * p, c)] =
                    *(const uint4*)(B + (size_t)(r + 32 * p) * NNODES + m0 + c);
        }
        __syncthreads();
        #pragma unroll
        for (int ks = 0; ks < 2; ks++) {
            const int kb = ks * 32 + lkb;
            bf8v ah[4], al[4], b8[4];
            #pragma unroll
            for (int i = 0; i < 4; i++) {
                ah[i] = lds_frag(&lAh[swz(wrow0 + 16 * i + lrow, kb)]);
                al[i] = lds_frag(&lAl[swz(wrow0 + 16 * i + lrow, kb)]);
            }
            #pragma unroll
            for (int j = 0; j < 4; j++)
                b8[j] = lds_frag(&lB[swz(wcol0 + 16 * j + lrow, kb)]);
            #pragma unroll
            for (int i = 0; i < 4; i++)
                #pragma unroll
                for (int j = 0; j < 4; j++) {
                    acc[i][j] = mfma16(ah[i], b8[j], acc[i][j]);
                    acc[i][j] = mfma16(al[i], b8[j], acc[i][j]);
                }
        }
    }
    #pragma unroll
    for (int i = 0; i < 4; i++)
        #pragma unroll
        for (int j = 0; j < 4; j++)
            #pragma unroll
            for (int reg = 0; reg < 4; reg++) {
                int row = wrow0 + 16 * i + (lane >> 4) * 4 + reg;
                int col = wcol0 + 16 * j + (lane & 15);
                X[(size_t)(n0 + row) * KXX + dir * 1024 + e * 128 + col] =
                    acc[i][j][reg];
            }
}

// ---------------- K3: G = X @ W'^T + b  (X fp32 -> hi/lo; W' bf16) -----------
__global__ __launch_bounds__(256, 3) void k3_gates(const float* __restrict__ X,
        const u16* __restrict__ WT, const float* __restrict__ bv,
        float* __restrict__ G)
{
    const int nt = blockIdx.x, ct = blockIdx.y;
    const int n0 = nt * 128, j0 = ct * 128;
    const int tid = threadIdx.x, lane = tid & 63, wv = tid >> 6;
    const int wrow0 = (wv & 1) * 64, wcol0 = (wv >> 1) * 64;
    const int lrow = lane & 15, lkb = (lane >> 4) * 8;
    __shared__ __align__(16) u16 lXh[128 * 64];
    __shared__ __align__(16) u16 lXl[128 * 64];
    __shared__ __align__(16) u16 lW [128 * 64];

    f4v acc[4][4];
    #pragma unroll
    for (int i = 0; i < 4; i++)
        #pragma unroll
        for (int j = 0; j < 4; j++)
            #pragma unroll
            for (int q = 0; q < 4; q++) acc[i][j][q] = 0.f;

    for (int c0 = 0; c0 < KXX; c0 += 64) {
        __syncthreads();
        int r = tid >> 3, cc = (tid & 7) * 8;
        #pragma unroll
        for (int p = 0; p < 4; p++) {
            u16 vh[8], vl[8];
            split8(X + (size_t)(n0 + r + 32 * p) * KXX + c0 + cc, vh, vl);
            *(uint4*)&lXh[swz(r + 32 * p, cc)] = *(const uint4*)vh;
            *(uint4*)&lXl[swz(r + 32 * p, cc)] = *(const uint4*)vl;
            *(uint4*)&lW [swz(r + 32 * p, cc)] =
                *(const uint4*)(WT + (size_t)(j0 + r + 32 * p) * KXX + c0 + cc);
        }
        __syncthreads();
        #pragma unroll
        for (int ks = 0; ks < 2; ks++) {
            const int kb = ks * 32 + lkb;
            bf8v ah[4], al[4], b8[4];
            #pragma unroll
            for (int i = 0; i < 4; i++) {
                ah[i] = lds_frag(&lXh[swz(wrow0 + 16 * i + lrow, kb)]);
                al[i] = lds_frag(&lXl[swz(wrow0 + 16 * i + lrow, kb)]);
            }
            #pragma unroll
            for (int j = 0; j < 4; j++)
                b8[j] = lds_frag(&lW[swz(wcol0 + 16 * j + lrow, kb)]);
            #pragma unroll
            for (int i = 0; i < 4; i++)
                #pragma unroll
                for (int j = 0; j < 4; j++) {
                    acc[i][j] = mfma16(ah[i], b8[j], acc[i][j]);
                    acc[i][j] = mfma16(al[i], b8[j], acc[i][j]);
                }
        }
    }
    #pragma unroll
    for (int i = 0; i < 4; i++)
        #pragma unroll
        for (int j = 0; j < 4; j++)
            #pragma unroll
            for (int reg = 0; reg < 4; reg++) {
                int row = wrow0 + 16 * i + (lane >> 4) * 4 + reg;
                int col = wcol0 + 16 * j + (lane & 15);
                G[(size_t)(n0 + row) * NG + j0 + col] = acc[i][j][reg] + bv[j0 + col];
            }
}

// ---------------- K4: LayerNorm gates + GRU update; one wave per row ---------
__global__ void k4_ln(const float* __restrict__ G, const float* __restrict__ gam,
                      const float* __restrict__ bet, float* __restrict__ h,
                      float* __restrict__ X, float* __restrict__ out)
{
    const int n = blockIdx.x * 4 + (threadIdx.x >> 6);
    const int t = threadIdx.x & 63;
    const float* g = G + (size_t)n * NG;
    float a0 = g[t],       a0b = g[t + 64];
    float a1 = g[128 + t], a1b = g[192 + t];
    float a2 = g[256 + t], a2b = g[320 + t];
    float a3 = g[384 + t], a3b = g[448 + t];

    auto redsum = [](float v) {
        #pragma unroll
        for (int m = 32; m >= 1; m >>= 1) v += __shfl_xor(v, m, 64);
        return v;
    };

    float s0 = redsum(a0 + a0b) * (1.f / 128.f);
    float q0 = redsum(a0 * a0 + a0b * a0b) * (1.f / 128.f);
    float rs0 = rsqrtf(fmaxf(q0 - s0 * s0, 0.f) + 1e-5f);
    float x0  = (a0  - s0) * rs0 * gam[t]      + bet[t];
    float x0b = (a0b - s0) * rs0 * gam[t + 64] + bet[t + 64];
    float r  = 1.f / (1.f + expf(-x0));
    float rb = 1.f / (1.f + expf(-x0b));

    float s1 = redsum(a1 + a1b) * (1.f / 128.f);
    float q1 = redsum(a1 * a1 + a1b * a1b) * (1.f / 128.f);
    float rs1 = rsqrtf(fmaxf(q1 - s1 * s1, 0.f) + 1e-5f);
    float x1  = (a1  - s1) * rs1 * gam[128 + t] + bet[128 + t];
    float x1b = (a1b - s1) * rs1 * gam[192 + t] + bet[192 + t];
    float z  = 1.f / (1.f + expf(-x1));
    float zb = 1.f / (1.f + expf(-x1b));

    float c2  = a2  + r  * a3;
    float c2b = a2b + rb * a3b;
    float s2 = redsum(c2 + c2b) * (1.f / 128.f);
    float q2 = redsum(c2 * c2 + c2b * c2b) * (1.f / 128.f);
    float rs2 = rsqrtf(fmaxf(q2 - s2 * s2, 0.f) + 1e-5f);
    float x2  = (c2  - s2) * rs2 * gam[256 + t] + bet[256 + t];
    float x2b = (c2b - s2) * rs2 * gam[320 + t] + bet[320 + t];
    float nn  = tanhf(x2);
    float nnb = tanhf(x2b);

    float ho  = h[(size_t)n * HDIM + t];
    float hob = h[(size_t)n * HDIM + t + 64];
    float hn  = (1.f - z)  * nn  + z  * ho;
    float hnb = (1.f - zb) * nnb + zb * hob;
    h[(size_t)n * HDIM + t]      = hn;
    h[(size_t)n * HDIM + t + 64] = hnb;
    X[(size_t)n * KXX + 2048 + t]      = hn;
    X[(size_t)n * KXX + 2048 + t + 64] = hnb;
    out[(size_t)n * HDIM + t]      = hn;
    out[(size_t)n * HDIM + t + 64] = hnb;
}

// ---------------------------------------------------------------------------
extern "C" void kernel_launch(void* const* d_in, const int* in_sizes, int n_in,
                              void* d_out, int out_size, void* d_ws, size_t ws_size,
                              hipStream_t stream)
{
    const float* A    = (const float*)d_in[0];
    const float* nst  = (const float*)d_in[1];
    const int*   ids  = (const int*)d_in[2];
    const float* emb  = (const float*)d_in[3];
    const float* Wi   = (const float*)d_in[4];
    const float* bi   = (const float*)d_in[5];
    const float* Wo   = (const float*)d_in[6];
    const float* bo   = (const float*)d_in[7];
    const float* Wn   = (const float*)d_in[8];
    const float* bn   = (const float*)d_in[9];
    const float* Wx   = (const float*)d_in[10];
    const float* bx   = (const float*)d_in[11];
    const float* Wh   = (const float*)d_in[12];
    const float* bh   = (const float*)d_in[13];
    const float* gam  = (const float*)d_in[14];
    const float* bet  = (const float*)d_in[15];

    char* ws = (char*)d_ws;
    size_t off = 0;
    auto alloc = [&](size_t bytes) {
        size_t cur = off; off += (bytes + 255) & ~(size_t)255; return (void*)(ws + cur);
    };
    float* h   = (float*)alloc((size_t)NNODES * HDIM * 4);
    u16*   hoT = (u16*)  alloc((size_t)2 * NE * HDIM * NNODES * 2);
    float* X   = (float*)alloc((size_t)NNODES * KXX * 4);
    float* G   = (float*)alloc((size_t)NNODES * NG * 4);
    u16*   WT  = (u16*)  alloc((size_t)NG * KXX * 2);
    float* bv  = (float*)alloc((size_t)NG * 4);

    // ws diagnostic: too-small scratch -> launch nothing -> absmax ~= max|ref|.
    if (off > ws_size) return;

    kprep<<<512, 256, 0, stream>>>(Wx, bx, Wh, bh, WT, bv);
    k0_init<<<256, 128, 0, stream>>>(nst, ids, emb, Wi, bi, h, X);
    for (int it = 0; it < 2; it++) {
        k1_hoT<<<dim3(32, 8, 2), 256, 0, stream>>>(h, Wo, bo, Wn, bn, hoT);
        k2_msg<<<512, 256, 0, stream>>>(A, hoT, X);
        k3_gates<<<dim3(32, 4), 256, 0, stream>>>(X, WT, bv, G);
        k4_ln<<<1024, 256, 0, stream>>>(G, gam, bet, h, X, (float*)d_out);
    }
    (void)in_sizes; (void)n_in; (void)out_size;
}